// Round 9
// baseline (163.111 us; speedup 1.0000x reference)
//
#include <hip/hip_runtime.h>

typedef __attribute__((ext_vector_type(8))) short bf16x8;
typedef __attribute__((ext_vector_type(4))) float fx4;

struct __attribute__((aligned(8))) sh4 { short x, y, z, w; };

// ---------------- workspace layout (BYTE offsets) ----------------
#define OPART_B   0u          // bf16 [b][s(6)][n(4096)][64]  unnormalized O partials
#define LSUM_B    12582912u   // fp32 [b][s(6)][n]
#define SMALL_B   12976128u   // fp32 [b][c][n]  conv output (coalesced for upsample)
#define L2M_B     17170432u   // fp32 [b][64][64] channel-attn logits
#define C1B_B     17235968u   // bf16 [b][n][64]
#define QB_B      19333120u   // bf16 [b][n][64]
#define KB_B      21430272u   // bf16 [b][n][64]
#define VCN_B     23527424u   // bf16 [b][c][n]   (flash PV A-operand)
#define VNC_B     25624576u   // bf16 [b][n][c]   (out2 B-operand)
#define Q2B_B     27721728u   // bf16 [b][c][n]
#define K2B_B     29818880u   // bf16 [b][c][n]
// total ~31.9 MB

static __device__ __forceinline__ short f2bf(float f) {
  unsigned u = __float_as_uint(f);
  unsigned r = (u + 0x7FFFu + ((u >> 16) & 1u)) >> 16;
  return (short)r;
}
static __device__ __forceinline__ short f2bf_fast(float f) {   // round-half-up, positives
  return (short)((__float_as_uint(f) + 0x8000u) >> 16);
}
static __device__ __forceinline__ float bf2f(short s) {
  return __uint_as_float(((unsigned)(unsigned short)s) << 16);
}
// load 8 consecutive fp32 -> bf16x8 A/B fragment
static __device__ __forceinline__ bf16x8 ld8f(const float* p) {
  float4 p0 = *(const float4*)p;
  float4 p1 = *(const float4*)(p + 4);
  bf16x8 r;
  r[0] = f2bf(p0.x); r[1] = f2bf(p0.y); r[2] = f2bf(p0.z); r[3] = f2bf(p0.w);
  r[4] = f2bf(p1.x); r[5] = f2bf(p1.y); r[6] = f2bf(p1.z); r[7] = f2bf(p1.w);
  return r;
}

// ---------------- K1: patch-merge + LayerNorm + MFMA 256->64 projection (+ L2M zero) ----------------
__global__ __launch_bounds__(256) void patchln_kernel(
    const float* __restrict__ x, const float* __restrict__ gamma,
    const float* __restrict__ beta, const float* __restrict__ pm_w,
    const float* __restrict__ pm_b, short* __restrict__ c1b, float* __restrict__ l2m)
{
  __shared__ short tnb[32*264];     // bf16 [j][c] padded stride 264
  __shared__ float red_s[512];
  __shared__ float mu_s[32], rs_s[32];
  const int b   = blockIdx.y;
  const int i   = blockIdx.x >> 1;
  const int jh  = blockIdx.x & 1;
  const int tid = threadIdx.x;
  const int j   = tid & 31;
  const int g8  = tid >> 5;
  const int jj  = jh*32 + j;

  if (blockIdx.x == 0) {            // zero channel-attn logits for batch b
    #pragma unroll
    for (int k = 0; k < 16; ++k) l2m[(size_t)b*4096 + k*256 + tid] = 0.0f;
  }

  float vals[32];
  float sm = 0.f, sq = 0.f;
  #pragma unroll
  for (int k = 0; k < 16; ++k) {
    int p  = g8*16 + k;             // 0..127
    int cc = p & 63, di = p >> 6;
    float2 v2 = *(const float2*)&x[((size_t)(b*64 + cc)*128 + 2*i + di)*128 + 2*jj];
    vals[2*k]   = v2.x;
    vals[2*k+1] = v2.y;
    sm += v2.x + v2.y; sq += v2.x*v2.x + v2.y*v2.y;
  }
  red_s[g8*32 + j] = sm;
  red_s[256 + g8*32 + j] = sq;
  __syncthreads();
  if (tid < 32) {
    float s0 = 0.f, q0 = 0.f;
    #pragma unroll
    for (int g = 0; g < 8; ++g) { s0 += red_s[g*32 + tid]; q0 += red_s[256 + g*32 + tid]; }
    float mu  = s0 * (1.0f/256.0f);
    float var = q0 * (1.0f/256.0f) - mu*mu;
    mu_s[tid] = mu;
    rs_s[tid] = rsqrtf(var + 1e-5f);
  }
  __syncthreads();
  {
    float mu = mu_s[j], rs = rs_s[j];
    #pragma unroll
    for (int k = 0; k < 16; ++k) {
      int p  = g8*16 + k;
      int ca = p, cb = p + 128;
      tnb[j*264 + ca] = f2bf((vals[2*k]   - mu)*rs*gamma[ca] + beta[ca]);
      tnb[j*264 + cb] = f2bf((vals[2*k+1] - mu)*rs*gamma[cb] + beta[cb]);
    }
  }
  __syncthreads();

  const int w    = tid >> 6;
  const int lane = tid & 63;
  const int L15  = lane & 15;
  const int quad = lane >> 4;
  fx4 d0 = {0.f,0.f,0.f,0.f}, d1 = {0.f,0.f,0.f,0.f};
  #pragma unroll
  for (int kc = 0; kc < 8; ++kc) {
    bf16x8 a = ld8f(pm_w + (w*16 + L15)*256 + kc*32 + quad*8);   // inline fp32->bf16
    bf16x8 bf0 = *(const bf16x8*)&tnb[(L15)*264      + kc*32 + quad*8];
    bf16x8 bf1 = *(const bf16x8*)&tnb[(16 + L15)*264 + kc*32 + quad*8];
    d0 = __builtin_amdgcn_mfma_f32_16x16x32_bf16(a, bf0, d0, 0, 0, 0);
    d1 = __builtin_amdgcn_mfma_f32_16x16x32_bf16(a, bf1, d1, 0, 0, 0);
  }
  const int obase = w*16 + quad*4;
  float bias0 = pm_b[obase], bias1 = pm_b[obase+1], bias2 = pm_b[obase+2], bias3 = pm_b[obase+3];
  const int gn0 = i*64 + jh*32 + L15;
  sh4 s0; s0.x = f2bf(d0[0]+bias0); s0.y = f2bf(d0[1]+bias1); s0.z = f2bf(d0[2]+bias2); s0.w = f2bf(d0[3]+bias3);
  sh4 s1; s1.x = f2bf(d1[0]+bias0); s1.y = f2bf(d1[1]+bias1); s1.z = f2bf(d1[2]+bias2); s1.w = f2bf(d1[3]+bias3);
  *(sh4*)&c1b[((size_t)b*4096 + gn0)*64 + obase]      = s0;
  *(sh4*)&c1b[((size_t)b*4096 + gn0 + 16)*64 + obase] = s1;
}

// ---------------- K2: 5 projections via MFMA; fp32 weights inline; packed [c][n] via LDS transpose ----------------
__global__ __launch_bounds__(256) void proj5_kernel(
    const short* __restrict__ c1b,
    const float* __restrict__ w2f, const float* __restrict__ w3f, const float* __restrict__ w4f,
    const float* __restrict__ w5f, const float* __restrict__ w6f,
    const float* __restrict__ b2, const float* __restrict__ b3, const float* __restrict__ b4,
    const float* __restrict__ b5, const float* __restrict__ b6,
    short* __restrict__ qb, short* __restrict__ kb,
    short* __restrict__ vcn, short* __restrict__ vnc,
    short* __restrict__ q2b, short* __restrict__ k2b)
{
  __shared__ short ldsT[4*16*72];   // per-wave 16n x 72-stride transpose tile
  const int b    = blockIdx.y;
  const int tid  = threadIdx.x;
  const int w    = tid >> 6;
  const int nsub = w & 1;
  const int pg   = w >> 1;
  const int lane = tid & 63;
  const int L15  = lane & 15;
  const int quad = lane >> 4;
  const int gn0  = blockIdx.x*32 + nsub*16;
  const int gn   = gn0 + L15;
  short* T = ldsT + w*16*72;

  bf16x8 bf0 = *(const bf16x8*)&c1b[((size_t)b*4096 + gn)*64 + quad*8];
  bf16x8 bf1 = *(const bf16x8*)&c1b[((size_t)b*4096 + gn)*64 + quad*8 + 32];

  if (pg == 0) {
    const float* wp[2] = {w2f, w3f};
    const float* bp[2] = {b2, b3};
    #pragma unroll
    for (int p = 0; p < 2; ++p) {
      short* dst = (p == 0) ? qb : kb;
      #pragma unroll
      for (int mt = 0; mt < 4; ++mt) {
        bf16x8 a0 = ld8f(wp[p] + (mt*16 + L15)*64 + quad*8);
        bf16x8 a1 = ld8f(wp[p] + (mt*16 + L15)*64 + quad*8 + 32);
        fx4 d = {0.f,0.f,0.f,0.f};
        d = __builtin_amdgcn_mfma_f32_16x16x32_bf16(a0, bf0, d, 0, 0, 0);
        d = __builtin_amdgcn_mfma_f32_16x16x32_bf16(a1, bf1, d, 0, 0, 0);
        const int ob = mt*16 + quad*4;
        sh4 s; s.x = f2bf(d[0]+bp[p][ob]); s.y = f2bf(d[1]+bp[p][ob+1]);
        s.z = f2bf(d[2]+bp[p][ob+2]); s.w = f2bf(d[3]+bp[p][ob+3]);
        *(sh4*)&dst[((size_t)b*4096 + gn)*64 + ob] = s;
      }
    }
    #pragma unroll
    for (int mt = 0; mt < 4; ++mt) {
      bf16x8 a0 = ld8f(w4f + (mt*16 + L15)*64 + quad*8);
      bf16x8 a1 = ld8f(w4f + (mt*16 + L15)*64 + quad*8 + 32);
      fx4 d = {0.f,0.f,0.f,0.f};
      d = __builtin_amdgcn_mfma_f32_16x16x32_bf16(a0, bf0, d, 0, 0, 0);
      d = __builtin_amdgcn_mfma_f32_16x16x32_bf16(a1, bf1, d, 0, 0, 0);
      const int ob = mt*16 + quad*4;
      sh4 s; s.x = f2bf(d[0]+b4[ob]); s.y = f2bf(d[1]+b4[ob+1]);
      s.z = f2bf(d[2]+b4[ob+2]); s.w = f2bf(d[3]+b4[ob+3]);
      *(sh4*)&vnc[((size_t)b*4096 + gn)*64 + ob] = s;
      *(sh4*)&T[L15*72 + ob] = s;
    }
    {
      const int o = lane;
      bf16x8 r0, r1;
      #pragma unroll
      for (int n = 0; n < 8; ++n) r0[n] = T[n*72 + o];
      #pragma unroll
      for (int n = 0; n < 8; ++n) r1[n] = T[(n+8)*72 + o];
      *(bf16x8*)&vcn[(size_t)b*262144 + (size_t)o*4096 + gn0]     = r0;
      *(bf16x8*)&vcn[(size_t)b*262144 + (size_t)o*4096 + gn0 + 8] = r1;
    }
  } else {
    const float* wp[2] = {w5f, w6f};
    const float* bp[2] = {b5, b6};
    #pragma unroll
    for (int p = 0; p < 2; ++p) {
      short* dst = (p == 0) ? q2b : k2b;
      #pragma unroll
      for (int mt = 0; mt < 4; ++mt) {
        bf16x8 a0 = ld8f(wp[p] + (mt*16 + L15)*64 + quad*8);
        bf16x8 a1 = ld8f(wp[p] + (mt*16 + L15)*64 + quad*8 + 32);
        fx4 d = {0.f,0.f,0.f,0.f};
        d = __builtin_amdgcn_mfma_f32_16x16x32_bf16(a0, bf0, d, 0, 0, 0);
        d = __builtin_amdgcn_mfma_f32_16x16x32_bf16(a1, bf1, d, 0, 0, 0);
        const int ob = mt*16 + quad*4;
        sh4 s; s.x = f2bf(d[0]+bp[p][ob]); s.y = f2bf(d[1]+bp[p][ob+1]);
        s.z = f2bf(d[2]+bp[p][ob+2]); s.w = f2bf(d[3]+bp[p][ob+3]);
        *(sh4*)&T[L15*72 + ob] = s;
      }
      const int o = lane;
      bf16x8 r0, r1;
      #pragma unroll
      for (int n = 0; n < 8; ++n) r0[n] = T[n*72 + o];
      #pragma unroll
      for (int n = 0; n < 8; ++n) r1[n] = T[(n+8)*72 + o];
      *(bf16x8*)&dst[(size_t)b*262144 + (size_t)o*4096 + gn0]     = r0;
      *(bf16x8*)&dst[(size_t)b*262144 + (size_t)o*4096 + gn0 + 8] = r1;
    }
  }
}

// ---------------- K3: flash attention (S^T, packed b64 P-writes) + fused corr branch ----------------
// grid (32, 7, B): y<6 -> flash split y; y==6 -> channel-attn logits block (n0 = x*128).
__global__ __launch_bounds__(256) void flash_kernel(
    const short* __restrict__ Qb, const short* __restrict__ Kb,
    const short* __restrict__ Vcn, short* __restrict__ opart, float* __restrict__ lsum,
    const short* __restrict__ q2b, const short* __restrict__ k2b, float* __restrict__ L2M)
{
  __shared__ short lds_s[24576];   // kt dbuf 2*4096 | vs dbuf 2*4096 | ps 128*64
  const int b    = blockIdx.z;
  const int s    = blockIdx.y;
  const int tid  = threadIdx.x;
  const int w    = tid >> 6;
  const int lane = tid & 63;
  const int L15  = lane & 15;
  const int quad = lane >> 4;

  if (s == 6) {                    // ---- corr: L[c][d] += sum_n q2[c,n] k2[d,n] ----
    const int n0 = blockIdx.x * 128;
    const short* qg = q2b + (size_t)b*262144;
    const short* kg = k2b + (size_t)b*262144;
    fx4 D[4] = {{0.f,0.f,0.f,0.f},{0.f,0.f,0.f,0.f},{0.f,0.f,0.f,0.f},{0.f,0.f,0.f,0.f}};
    #pragma unroll
    for (int kc = 0; kc < 4; ++kc) {
      bf16x8 a = *(const bf16x8*)&qg[(w*16 + L15)*4096 + n0 + kc*32 + quad*8];
      #pragma unroll
      for (int nt = 0; nt < 4; ++nt) {
        bf16x8 bb = *(const bf16x8*)&kg[(nt*16 + L15)*4096 + n0 + kc*32 + quad*8];
        D[nt] = __builtin_amdgcn_mfma_f32_16x16x32_bf16(a, bb, D[nt], 0, 0, 0);
      }
    }
    float* Lb = L2M + (size_t)b*4096;
    #pragma unroll
    for (int nt = 0; nt < 4; ++nt)
      #pragma unroll
      for (int r = 0; r < 4; ++r)
        atomicAdd(&Lb[(w*16 + quad*4 + r)*64 + nt*16 + L15], D[nt][r]);
    return;
  }

  short* ktb = lds_s;
  short* vsb = lds_s + 8192;
  short* ps  = lds_s + 16384;

  const int q0   = blockIdx.x << 7;
  const int t0   = (s < 4) ? s*11 : 44 + (s - 4)*10;
  const int cnt  = (s < 4) ? 11 : 10;
  const int jbase = w*32;

  const short* Qg = Qb  + (size_t)b*262144;
  const short* Kg = Kb  + (size_t)b*262144;
  const short* Vg = Vcn + (size_t)b*262144;

  bf16x8 qa[2][2];
  #pragma unroll
  for (int jt = 0; jt < 2; ++jt)
    #pragma unroll
    for (int h = 0; h < 2; ++h)
      qa[jt][h] = *(const bf16x8*)(Qg + (size_t)(q0 + jbase + jt*16 + L15)*64 + h*32 + quad*8);

  bf16x8 ones;
  #pragma unroll
  for (int u = 0; u < 8; ++u) ones[u] = (short)0x3F80;

  const int si  = tid >> 2;
  const int scb = (tid & 3) * 2;
  const int s0k = scb ^ (si & 7);
  const int s1k = s0k ^ 1;

  {
    const int i0 = t0 << 6;
    bf16x8 kr0 = *(const bf16x8*)(Kg + (size_t)(i0 + si)*64 + scb*8);
    bf16x8 kr1 = *(const bf16x8*)(Kg + (size_t)(i0 + si)*64 + scb*8 + 8);
    bf16x8 vr0 = *(const bf16x8*)(Vg + (size_t)si*4096 + i0 + (tid&3)*16);
    bf16x8 vr1 = *(const bf16x8*)(Vg + (size_t)si*4096 + i0 + (tid&3)*16 + 8);
    *(bf16x8*)(ktb + si*64 + s0k*8) = kr0;
    *(bf16x8*)(ktb + si*64 + s1k*8) = kr1;
    *(bf16x8*)(vsb + si*64 + s0k*8) = vr0;
    *(bf16x8*)(vsb + si*64 + s1k*8) = vr1;
  }
  __syncthreads();

  fx4 oacc[2][4];
  #pragma unroll
  for (int jt = 0; jt < 2; ++jt)
    #pragma unroll
    for (int ct = 0; ct < 4; ++ct) oacc[jt][ct] = (fx4){0.f,0.f,0.f,0.f};
  fx4 lacc[2] = {{0.f,0.f,0.f,0.f},{0.f,0.f,0.f,0.f}};

  const int cbx0 = quad       ^ (L15 & 7);
  const int cbx1 = (quad + 4) ^ (L15 & 7);
  const int jk   = L15 & 7;
  const int pu   = (quad >> 1);
  const int ph   = (quad & 1) << 2;

  for (int t = 0; t < cnt; ++t) {
    const short* kt = ktb + (t & 1)*4096;
    const short* vv = vsb + (t & 1)*4096;
    short* ktn = ktb + ((t + 1) & 1)*4096;
    short* vsn = vsb + ((t + 1) & 1)*4096;

    bf16x8 kr0, kr1, vr0, vr1;
    const bool pf = (t < cnt - 1);
    if (pf) {
      const int i0n = (t0 + t + 1) << 6;
      kr0 = *(const bf16x8*)(Kg + (size_t)(i0n + si)*64 + scb*8);
      kr1 = *(const bf16x8*)(Kg + (size_t)(i0n + si)*64 + scb*8 + 8);
      vr0 = *(const bf16x8*)(Vg + (size_t)si*4096 + i0n + (tid&3)*16);
      vr1 = *(const bf16x8*)(Vg + (size_t)si*4096 + i0n + (tid&3)*16 + 8);
    }

    // S^T = K Q^T
    fx4 d2[4][2];
    #pragma unroll
    for (int mt = 0; mt < 4; ++mt)
      #pragma unroll
      for (int jt = 0; jt < 2; ++jt) d2[mt][jt] = (fx4){0.f,0.f,0.f,0.f};
    #pragma unroll
    for (int mt = 0; mt < 4; ++mt) {
      bf16x8 ak0 = *(const bf16x8*)(kt + (mt*16 + L15)*64 + cbx0*8);
      bf16x8 ak1 = *(const bf16x8*)(kt + (mt*16 + L15)*64 + cbx1*8);
      d2[mt][0] = __builtin_amdgcn_mfma_f32_16x16x32_bf16(ak0, qa[0][0], d2[mt][0], 0, 0, 0);
      d2[mt][1] = __builtin_amdgcn_mfma_f32_16x16x32_bf16(ak0, qa[1][0], d2[mt][1], 0, 0, 0);
      d2[mt][0] = __builtin_amdgcn_mfma_f32_16x16x32_bf16(ak1, qa[0][1], d2[mt][0], 0, 0, 0);
      d2[mt][1] = __builtin_amdgcn_mfma_f32_16x16x32_bf16(ak1, qa[1][1], d2[mt][1], 0, 0, 0);
    }

    // raw exp; packed b64 P-writes
    #pragma unroll
    for (int mt = 0; mt < 4; ++mt) {
      const int slot0 = ((mt*2 + pu) ^ jk) << 3;
      #pragma unroll
      for (int jt = 0; jt < 2; ++jt) {
        const int j = jbase + jt*16 + L15;
        sh4 pv;
        pv.x = f2bf_fast(__expf(d2[mt][jt][0]));
        pv.y = f2bf_fast(__expf(d2[mt][jt][1]));
        pv.z = f2bf_fast(__expf(d2[mt][jt][2]));
        pv.w = f2bf_fast(__expf(d2[mt][jt][3]));
        *(sh4*)&ps[j*64 + slot0 + ph] = pv;
      }
    }

    bf16x8 pb[2][2];
    #pragma unroll
    for (int jt = 0; jt < 2; ++jt) {
      const int jrow = jbase + jt*16 + L15;
      pb[jt][0] = *(const bf16x8*)&ps[jrow*64 + (((quad    ) ^ jk) << 3)];
      pb[jt][1] = *(const bf16x8*)&ps[jrow*64 + (((quad + 4) ^ jk) << 3)];
    }

    #pragma unroll
    for (int jt = 0; jt < 2; ++jt) {
      lacc[jt] = __builtin_amdgcn_mfma_f32_16x16x32_bf16(ones, pb[jt][0], lacc[jt], 0, 0, 0);
      lacc[jt] = __builtin_amdgcn_mfma_f32_16x16x32_bf16(ones, pb[jt][1], lacc[jt], 0, 0, 0);
    }

    #pragma unroll
    for (int ct = 0; ct < 4; ++ct) {
      bf16x8 va0 = *(const bf16x8*)(vv + (ct*16 + L15)*64 + cbx0*8);
      bf16x8 va1 = *(const bf16x8*)(vv + (ct*16 + L15)*64 + cbx1*8);
      #pragma unroll
      for (int jt = 0; jt < 2; ++jt) {
        oacc[jt][ct] = __builtin_amdgcn_mfma_f32_16x16x32_bf16(va0, pb[jt][0], oacc[jt][ct], 0, 0, 0);
        oacc[jt][ct] = __builtin_amdgcn_mfma_f32_16x16x32_bf16(va1, pb[jt][1], oacc[jt][ct], 0, 0, 0);
      }
    }

    if (pf) {
      *(bf16x8*)(ktn + si*64 + s0k*8) = kr0;
      *(bf16x8*)(ktn + si*64 + s1k*8) = kr1;
      *(bf16x8*)(vsn + si*64 + s0k*8) = vr0;
      *(bf16x8*)(vsn + si*64 + s1k*8) = vr1;
    }
    __syncthreads();
  }

  const size_t srow = ((size_t)(b*6 + s)*4096) + q0;
  #pragma unroll
  for (int jt = 0; jt < 2; ++jt) {
    const size_t nrow = srow + jbase + jt*16 + L15;
    #pragma unroll
    for (int ct = 0; ct < 4; ++ct) {
      sh4 sv;
      sv.x = f2bf(oacc[jt][ct][0]); sv.y = f2bf(oacc[jt][ct][1]);
      sv.z = f2bf(oacc[jt][ct][2]); sv.w = f2bf(oacc[jt][ct][3]);
      *(sh4*)&opart[nrow*64 + ct*16 + quad*4] = sv;
    }
    if (quad == 0) lsum[nrow] = lacc[jt][0];
  }
}

// ---------------- K5: fused channel-softmax + merge + out2 + final conv ----------------
// grid (128 n-tiles of 32, B), block 256. p2 (8KB) + cat 32x128 (8KB) in LDS, xor-swizzled.
__global__ __launch_bounds__(256) void tail_kernel(
    const short* __restrict__ opart, const float* __restrict__ lsum,
    const float* __restrict__ l2m, const short* __restrict__ vnc,
    const float* __restrict__ w1f, const float* __restrict__ b1,
    float* __restrict__ sml)
{
  __shared__ short p2[4096];
  __shared__ short cat[4096];
  const int b    = blockIdx.y;
  const int n0   = blockIdx.x << 5;
  const int tid  = threadIdx.x;
  const int w    = tid >> 6;
  const int lane = tid & 63;
  const int L15  = lane & 15;
  const int quad = lane >> 4;

  // phase 0: channel softmax (redundant per block, tiny): row c = tid (<64)
  if (tid < 64) {
    const float* Lr = l2m + (size_t)b*4096 + tid*64;
    float vrow[64];
    float mx = -1e30f;
    #pragma unroll
    for (int d4 = 0; d4 < 16; ++d4) {
      float4 v4 = *(const float4*)&Lr[d4*4];
      vrow[d4*4+0] = v4.x; vrow[d4*4+1] = v4.y; vrow[d4*4+2] = v4.z; vrow[d4*4+3] = v4.w;
      mx = fmaxf(mx, fmaxf(fmaxf(v4.x, v4.y), fmaxf(v4.z, v4.w)));
    }
    float sme = 0.f;
    #pragma unroll
    for (int d = 0; d < 64; ++d) { vrow[d] = __expf(vrow[d] - mx); sme += vrow[d]; }
    const float inv = 1.0f / sme;
    const int key = tid & 7;
    #pragma unroll
    for (int g = 0; g < 8; ++g) {
      bf16x8 pk;
      #pragma unroll
      for (int u = 0; u < 8; ++u) pk[u] = f2bf(vrow[g*8 + u] * inv);
      *(bf16x8*)&p2[tid*64 + ((g ^ key) << 3)] = pk;
    }
  }

  // phase 1: merge 6 flash partials -> cat cols 0..63 (32 rows x 8 threads)
  {
    const int nl = tid >> 3;
    const int c0 = (tid & 7) << 3;
    const int n  = n0 + nl;
    float l = 0.f;
    #pragma unroll
    for (int sp = 0; sp < 6; ++sp) l += lsum[((size_t)(b*6 + sp)*4096) + n];
    const float inv = 1.0f / l;
    float acc[8];
    #pragma unroll
    for (int u = 0; u < 8; ++u) acc[u] = 0.f;
    #pragma unroll
    for (int sp = 0; sp < 6; ++sp) {
      bf16x8 A0 = *(const bf16x8*)&opart[(((size_t)(b*6 + sp)*4096) + n)*64 + c0];
      #pragma unroll
      for (int u = 0; u < 8; ++u) acc[u] += bf2f(A0[u]);
    }
    const int key = nl & 7;
    const int g = (c0 >> 3) ^ key;
    bf16x8 s0;
    #pragma unroll
    for (int u = 0; u < 8; ++u) s0[u] = f2bf(acc[u]*inv);
    *(bf16x8*)&cat[nl*128 + (g << 3)] = s0;
  }
  __syncthreads();   // p2 ready; cat cols 0..63 done

  // phase 2: out2 = P2 @ V -> cat cols 64..127 (wave w: nsub = w&1, m-half = w>>1)
  {
    const int nl  = (w & 1)*16 + L15;
    const int n   = n0 + nl;
    const int mh  = w >> 1;
    const int key = L15 & 7;
    bf16x8 vb0 = *(const bf16x8*)&vnc[((size_t)b*4096 + n)*64 + quad*8];
    bf16x8 vb1 = *(const bf16x8*)&vnc[((size_t)b*4096 + n)*64 + quad*8 + 32];
    #pragma unroll
    for (int mi = 0; mi < 2; ++mi) {
      const int mt = mh*2 + mi;
      bf16x8 a0 = *(const bf16x8*)&p2[(mt*16 + L15)*64 + (((quad    ) ^ key) << 3)];
      bf16x8 a1 = *(const bf16x8*)&p2[(mt*16 + L15)*64 + (((quad + 4) ^ key) << 3)];
      fx4 d = {0.f,0.f,0.f,0.f};
      d = __builtin_amdgcn_mfma_f32_16x16x32_bf16(a0, vb0, d, 0, 0, 0);
      d = __builtin_amdgcn_mfma_f32_16x16x32_bf16(a1, vb1, d, 0, 0, 0);
      const int c = 64 + mt*16 + quad*4;
      const int g = (c >> 3) ^ key;
      sh4 sv; sv.x = f2bf(d[0]); sv.y = f2bf(d[1]); sv.z = f2bf(d[2]); sv.w = f2bf(d[3]);
      *(sh4*)&cat[nl*128 + (g << 3) + (quad & 1)*4] = sv;
    }
  }
  __syncthreads();

  // phase 3: conv 128->64 (wave w: nsub = w&1, m-half = w>>1), fp32 [c][n] out
  {
    const int nl  = (w & 1)*16 + L15;
    const int mh  = w >> 1;
    const int key = L15 & 7;
    bf16x8 bfr[4];
    #pragma unroll
    for (int kc = 0; kc < 4; ++kc) {
      const int g = (kc*4 + quad) ^ key;
      bfr[kc] = *(const bf16x8*)&cat[nl*128 + (g << 3)];
    }
    #pragma unroll
    for (int mi = 0; mi < 2; ++mi) {
      const int mt = mh*2 + mi;
      fx4 d = {0.f,0.f,0.f,0.f};
      #pragma unroll
      for (int kc = 0; kc < 4; ++kc) {
        bf16x8 a = ld8f(w1f + (mt*16 + L15)*128 + kc*32 + quad*8);
        d = __builtin_amdgcn_mfma_f32_16x16x32_bf16(a, bfr[kc], d, 0, 0, 0);
      }
      const int ob = mt*16 + quad*4;
      #pragma unroll
      for (int r = 0; r < 4; ++r)
        sml[((size_t)b*64 + ob + r)*4096 + n0 + nl] = d[r] + b1[ob + r];
    }
  }
}

// ---------------- K6: bilinear 2x upsample + residual — 2 horizontal pixels/thread ----------------
__global__ __launch_bounds__(256) void upsample_kernel(
    const float* __restrict__ sml, const float* __restrict__ x, float* __restrict__ out)
{
  int idx = blockIdx.x*256 + threadIdx.x;     // 2,097,152 threads
  int jp = idx & 63;
  int I  = (idx >> 6) & 127;
  int bo = idx >> 13;
  int ih = I >> 1;
  int i0, i1; float wi0, wi1;
  if (I & 1) { i0 = ih;                 i1 = (ih < 63) ? ih+1 : 63; wi0 = 0.75f; wi1 = 0.25f; }
  else       { i0 = (ih > 0) ? ih-1 : 0; i1 = ih;                   wi0 = 0.25f; wi1 = 0.75f; }
  const int jm = (jp > 0)  ? jp-1 : 0;
  const int jx = (jp < 63) ? jp+1 : 63;
  const float* sp = sml + (size_t)bo*4096;
  float a0 = sp[i0*64 + jm], a1 = sp[i0*64 + jp], a2 = sp[i0*64 + jx];
  float b0 = sp[i1*64 + jm], b1v = sp[i1*64 + jp], b2v = sp[i1*64 + jx];
  float re0 = wi0*(0.25f*a0 + 0.75f*a1) + wi1*(0.25f*b0 + 0.75f*b1v);
  float re1 = wi0*(0.75f*a1 + 0.25f*a2) + wi1*(0.75f*b1v + 0.25f*b2v);
  const size_t obase = ((size_t)bo*128 + I)*128 + jp*2;
  float2 xr = *(const float2*)&x[obase];
  *(float2*)&out[obase] = make_float2(re0 + xr.x, re1 + xr.y);
}

// ---------------- host ----------------
extern "C" void kernel_launch(void* const* d_in, const int* in_sizes, int n_in,
                              void* d_out, int out_size, void* d_ws, size_t ws_size,
                              hipStream_t stream) {
  const float* x     = (const float*)d_in[0];
  const float* gamma = (const float*)d_in[1];
  const float* beta  = (const float*)d_in[2];
  const float* pm_w  = (const float*)d_in[3];
  const float* pm_b  = (const float*)d_in[4];
  const float* w2 = (const float*)d_in[5];  const float* b2 = (const float*)d_in[6];
  const float* w3 = (const float*)d_in[7];  const float* b3 = (const float*)d_in[8];
  const float* w4 = (const float*)d_in[9];  const float* b4 = (const float*)d_in[10];
  const float* w5 = (const float*)d_in[11]; const float* b5 = (const float*)d_in[12];
  const float* w6 = (const float*)d_in[13]; const float* b6 = (const float*)d_in[14];
  const float* w1 = (const float*)d_in[15]; const float* b1 = (const float*)d_in[16];
  char* wsb  = (char*)d_ws;
  float* out = (float*)d_out;

  short* opart = (short*)(wsb + OPART_B);
  float* lsum  = (float*)(wsb + LSUM_B);
  float* sml   = (float*)(wsb + SMALL_B);
  float* l2m   = (float*)(wsb + L2M_B);
  short* c1b   = (short*)(wsb + C1B_B);
  short* qb    = (short*)(wsb + QB_B);
  short* kb    = (short*)(wsb + KB_B);
  short* vcn   = (short*)(wsb + VCN_B);
  short* vnc   = (short*)(wsb + VNC_B);
  short* q2b   = (short*)(wsb + Q2B_B);
  short* k2b   = (short*)(wsb + K2B_B);

  patchln_kernel<<<dim3(128,4), dim3(256), 0, stream>>>(x, gamma, beta, pm_w, pm_b, c1b, l2m);
  proj5_kernel<<<dim3(128,4), dim3(256), 0, stream>>>(c1b, w2, w3, w4, w5, w6,
      b2, b3, b4, b5, b6, qb, kb, vcn, vnc, q2b, k2b);
  flash_kernel<<<dim3(32,7,4), dim3(256), 0, stream>>>(qb, kb, vcn, opart, lsum, q2b, k2b, l2m);
  tail_kernel<<<dim3(128,4), dim3(256), 0, stream>>>(opart, lsum, l2m, vnc, w1, b1, sml);
  upsample_kernel<<<dim3(8192), dim3(256), 0, stream>>>(sml, x, out);
}

// Round 10
// 152.891 us; speedup vs baseline: 1.0668x; 1.0668x over previous
//
#include <hip/hip_runtime.h>

typedef __attribute__((ext_vector_type(8))) short bf16x8;
typedef __attribute__((ext_vector_type(4))) float fx4;

struct __attribute__((aligned(8))) sh4 { short x, y, z, w; };

// ---------------- workspace layout (BYTE offsets) ----------------
#define OPART_B   0u          // bf16 [b][s(6)][n(4096)][64]  unnormalized O partials
#define LSUM_B    12582912u   // fp32 [b][s(6)][n]
#define SMALL_B   12976128u   // fp32 [b][c][n]  conv output (coalesced for upsample)
#define L2M_B     17170432u   // fp32 [b][64][64] channel-attn logits
#define PMB_B     17235968u   // bf16 pm_w [o][256]
#define W2B_B     17268736u   // bf16 [o][64]
#define W3B_B     17276928u
#define W4B_B     17285120u
#define W5B_B     17293312u
#define W6B_B     17301504u
#define W1B_B     17309696u   // bf16 [o][128]
#define QB_B      17326080u   // bf16 [b][n][64]
#define KB_B      19423232u   // bf16 [b][n][64]
#define VCN_B     21520384u   // bf16 [b][c][n]   (flash PV A-operand)
#define VNC_B     23617536u   // bf16 [b][n][c]   (out2 B-operand)
#define Q2B_B     25714688u   // bf16 [b][c][n]
#define K2B_B     27811840u   // bf16 [b][c][n]
// total ~29.9 MB

static __device__ __forceinline__ short f2bf(float f) {
  unsigned u = __float_as_uint(f);
  unsigned r = (u + 0x7FFFu + ((u >> 16) & 1u)) >> 16;
  return (short)r;
}
static __device__ __forceinline__ short f2bf_fast(float f) {   // round-half-up, positives
  return (short)((__float_as_uint(f) + 0x8000u) >> 16);
}
static __device__ __forceinline__ float bf2f(short s) {
  return __uint_as_float(((unsigned)(unsigned short)s) << 16);
}

// ---------------- K0: weights -> bf16 (once), zero logits ----------------
__global__ __launch_bounds__(256) void prep_kernel(
    const float* __restrict__ pm_w, const float* __restrict__ w2,
    const float* __restrict__ w3,  const float* __restrict__ w4,
    const float* __restrict__ w5,  const float* __restrict__ w6,
    const float* __restrict__ w1,  char* __restrict__ wsb)
{
  int tid = blockIdx.x * 256 + threadIdx.x;   // 16384 threads
  ((short*)(wsb + PMB_B))[tid] = f2bf(pm_w[tid]);
  if (tid < 4096) {
    ((short*)(wsb + W2B_B))[tid] = f2bf(w2[tid]);
    ((short*)(wsb + W3B_B))[tid] = f2bf(w3[tid]);
    ((short*)(wsb + W4B_B))[tid] = f2bf(w4[tid]);
    ((short*)(wsb + W5B_B))[tid] = f2bf(w5[tid]);
    ((short*)(wsb + W6B_B))[tid] = f2bf(w6[tid]);
  }
  if (tid < 8192) ((short*)(wsb + W1B_B))[tid] = f2bf(w1[tid]);
  ((float*)(wsb + L2M_B))[tid] = 0.0f;
}

// ---------------- K1: FUSED patch-merge + LayerNorm + pm-projection + 5 QKV projections ----------------
// grid (128 = i*2+jh, B), block 256. Each block owns n in [i*64+jh*32, +32).
// c1 tile lives only in LDS (32n x 64c, granule-xor swizzle).
__global__ __launch_bounds__(256) void patchproj_kernel(
    const float* __restrict__ x, const float* __restrict__ gamma,
    const float* __restrict__ beta, const short* __restrict__ pmb,
    const float* __restrict__ pm_b,
    const short* __restrict__ w2b, const short* __restrict__ w3b, const short* __restrict__ w4b,
    const short* __restrict__ w5b, const short* __restrict__ w6b,
    const float* __restrict__ b2, const float* __restrict__ b3, const float* __restrict__ b4,
    const float* __restrict__ b5, const float* __restrict__ b6,
    short* __restrict__ qb, short* __restrict__ kb,
    short* __restrict__ vcn, short* __restrict__ vnc,
    short* __restrict__ q2b, short* __restrict__ k2b)
{
  __shared__ short tnb[32*264];     // bf16 [j][c] padded stride 264 (LN input)
  __shared__ short c1t[32*64];      // bf16 [n-local][c] xor-swizzled (projection input)
  __shared__ short ldsT[4*16*72];   // per-wave transpose tile for [c][n] outputs
  __shared__ float red_s[512];
  __shared__ float mu_s[32], rs_s[32];
  const int b   = blockIdx.y;
  const int i   = blockIdx.x >> 1;
  const int jh  = blockIdx.x & 1;
  const int tid = threadIdx.x;
  const int j   = tid & 31;
  const int g8  = tid >> 5;
  const int jj  = jh*32 + j;

  // ---- phase A: patch-merge load + LN statistics ----
  float vals[32];
  float sm = 0.f, sq = 0.f;
  #pragma unroll
  for (int k = 0; k < 16; ++k) {
    int p  = g8*16 + k;             // 0..127
    int cc = p & 63, di = p >> 6;
    float2 v2 = *(const float2*)&x[((size_t)(b*64 + cc)*128 + 2*i + di)*128 + 2*jj];
    vals[2*k]   = v2.x;
    vals[2*k+1] = v2.y;
    sm += v2.x + v2.y; sq += v2.x*v2.x + v2.y*v2.y;
  }
  red_s[g8*32 + j] = sm;
  red_s[256 + g8*32 + j] = sq;
  __syncthreads();
  if (tid < 32) {
    float s0 = 0.f, q0 = 0.f;
    #pragma unroll
    for (int g = 0; g < 8; ++g) { s0 += red_s[g*32 + tid]; q0 += red_s[256 + g*32 + tid]; }
    float mu  = s0 * (1.0f/256.0f);
    float var = q0 * (1.0f/256.0f) - mu*mu;
    mu_s[tid] = mu;
    rs_s[tid] = rsqrtf(var + 1e-5f);
  }
  __syncthreads();
  {
    float mu = mu_s[j], rs = rs_s[j];
    #pragma unroll
    for (int k = 0; k < 16; ++k) {
      int p  = g8*16 + k;
      int ca = p, cb = p + 128;
      tnb[j*264 + ca] = f2bf((vals[2*k]   - mu)*rs*gamma[ca] + beta[ca]);
      tnb[j*264 + cb] = f2bf((vals[2*k+1] - mu)*rs*gamma[cb] + beta[cb]);
    }
  }
  __syncthreads();

  // ---- phase B: 256->64 projection; D -> c1t LDS (packed b64, xor-swizzled) ----
  const int w    = tid >> 6;
  const int lane = tid & 63;
  const int L15  = lane & 15;
  const int quad = lane >> 4;
  {
    fx4 d0 = {0.f,0.f,0.f,0.f}, d1 = {0.f,0.f,0.f,0.f};
    #pragma unroll
    for (int kc = 0; kc < 8; ++kc) {
      bf16x8 a  = *(const bf16x8*)&pmb[(w*16 + L15)*256 + kc*32 + quad*8];
      bf16x8 bf0 = *(const bf16x8*)&tnb[(L15)*264      + kc*32 + quad*8];
      bf16x8 bf1 = *(const bf16x8*)&tnb[(16 + L15)*264 + kc*32 + quad*8];
      d0 = __builtin_amdgcn_mfma_f32_16x16x32_bf16(a, bf0, d0, 0, 0, 0);
      d1 = __builtin_amdgcn_mfma_f32_16x16x32_bf16(a, bf1, d1, 0, 0, 0);
    }
    const int obase = w*16 + quad*4;
    float bias0 = pm_b[obase], bias1 = pm_b[obase+1], bias2 = pm_b[obase+2], bias3 = pm_b[obase+3];
    const int gq  = (obase >> 3);          // granule of this lane's 4 o's
    const int hh  = (quad & 1) * 4;        // half-granule offset
    const int key = L15 & 7;               // row swizzle key (same for row and row+16)
    sh4 s0; s0.x = f2bf(d0[0]+bias0); s0.y = f2bf(d0[1]+bias1); s0.z = f2bf(d0[2]+bias2); s0.w = f2bf(d0[3]+bias3);
    sh4 s1; s1.x = f2bf(d1[0]+bias0); s1.y = f2bf(d1[1]+bias1); s1.z = f2bf(d1[2]+bias2); s1.w = f2bf(d1[3]+bias3);
    *(sh4*)&c1t[(L15)*64      + ((gq ^ key) << 3) + hh] = s0;
    *(sh4*)&c1t[(16 + L15)*64 + ((gq ^ key) << 3) + hh] = s1;
  }
  __syncthreads();

  // ---- phase C: 5 projections (wave-specialized), c1 B-frags from LDS ----
  const int nsub = w & 1;
  const int pg   = w >> 1;
  const int gn0  = i*64 + jh*32 + nsub*16;
  const int gn   = gn0 + L15;
  const int nl   = nsub*16 + L15;
  const int key  = L15 & 7;
  short* T = ldsT + w*16*72;

  bf16x8 bf0 = *(const bf16x8*)&c1t[nl*64 + (((quad    ) ^ key) << 3)];
  bf16x8 bf1 = *(const bf16x8*)&c1t[nl*64 + (((quad + 4) ^ key) << 3)];

  if (pg == 0) {
    const short* wp[2] = {w2b, w3b};
    const float* bp[2] = {b2, b3};
    #pragma unroll
    for (int p = 0; p < 2; ++p) {
      short* dst = (p == 0) ? qb : kb;
      #pragma unroll
      for (int mt = 0; mt < 4; ++mt) {
        bf16x8 a0 = *(const bf16x8*)&wp[p][(mt*16 + L15)*64 + quad*8];
        bf16x8 a1 = *(const bf16x8*)&wp[p][(mt*16 + L15)*64 + quad*8 + 32];
        fx4 d = {0.f,0.f,0.f,0.f};
        d = __builtin_amdgcn_mfma_f32_16x16x32_bf16(a0, bf0, d, 0, 0, 0);
        d = __builtin_amdgcn_mfma_f32_16x16x32_bf16(a1, bf1, d, 0, 0, 0);
        const int ob = mt*16 + quad*4;
        sh4 s; s.x = f2bf(d[0]+bp[p][ob]); s.y = f2bf(d[1]+bp[p][ob+1]);
        s.z = f2bf(d[2]+bp[p][ob+2]); s.w = f2bf(d[3]+bp[p][ob+3]);
        *(sh4*)&dst[((size_t)b*4096 + gn)*64 + ob] = s;
      }
    }
    #pragma unroll
    for (int mt = 0; mt < 4; ++mt) {
      bf16x8 a0 = *(const bf16x8*)&w4b[(mt*16 + L15)*64 + quad*8];
      bf16x8 a1 = *(const bf16x8*)&w4b[(mt*16 + L15)*64 + quad*8 + 32];
      fx4 d = {0.f,0.f,0.f,0.f};
      d = __builtin_amdgcn_mfma_f32_16x16x32_bf16(a0, bf0, d, 0, 0, 0);
      d = __builtin_amdgcn_mfma_f32_16x16x32_bf16(a1, bf1, d, 0, 0, 0);
      const int ob = mt*16 + quad*4;
      sh4 s; s.x = f2bf(d[0]+b4[ob]); s.y = f2bf(d[1]+b4[ob+1]);
      s.z = f2bf(d[2]+b4[ob+2]); s.w = f2bf(d[3]+b4[ob+3]);
      *(sh4*)&vnc[((size_t)b*4096 + gn)*64 + ob] = s;
      *(sh4*)&T[L15*72 + ob] = s;
    }
    {
      const int o = lane;
      bf16x8 r0, r1;
      #pragma unroll
      for (int n = 0; n < 8; ++n) r0[n] = T[n*72 + o];
      #pragma unroll
      for (int n = 0; n < 8; ++n) r1[n] = T[(n+8)*72 + o];
      *(bf16x8*)&vcn[(size_t)b*262144 + (size_t)o*4096 + gn0]     = r0;
      *(bf16x8*)&vcn[(size_t)b*262144 + (size_t)o*4096 + gn0 + 8] = r1;
    }
  } else {
    const short* wp[2] = {w5b, w6b};
    const float* bp[2] = {b5, b6};
    #pragma unroll
    for (int p = 0; p < 2; ++p) {
      short* dst = (p == 0) ? q2b : k2b;
      #pragma unroll
      for (int mt = 0; mt < 4; ++mt) {
        bf16x8 a0 = *(const bf16x8*)&wp[p][(mt*16 + L15)*64 + quad*8];
        bf16x8 a1 = *(const bf16x8*)&wp[p][(mt*16 + L15)*64 + quad*8 + 32];
        fx4 d = {0.f,0.f,0.f,0.f};
        d = __builtin_amdgcn_mfma_f32_16x16x32_bf16(a0, bf0, d, 0, 0, 0);
        d = __builtin_amdgcn_mfma_f32_16x16x32_bf16(a1, bf1, d, 0, 0, 0);
        const int ob = mt*16 + quad*4;
        sh4 s; s.x = f2bf(d[0]+bp[p][ob]); s.y = f2bf(d[1]+bp[p][ob+1]);
        s.z = f2bf(d[2]+bp[p][ob+2]); s.w = f2bf(d[3]+bp[p][ob+3]);
        *(sh4*)&T[L15*72 + ob] = s;
      }
      const int o = lane;
      bf16x8 r0, r1;
      #pragma unroll
      for (int n = 0; n < 8; ++n) r0[n] = T[n*72 + o];
      #pragma unroll
      for (int n = 0; n < 8; ++n) r1[n] = T[(n+8)*72 + o];
      *(bf16x8*)&dst[(size_t)b*262144 + (size_t)o*4096 + gn0]     = r0;
      *(bf16x8*)&dst[(size_t)b*262144 + (size_t)o*4096 + gn0 + 8] = r1;
    }
  }
}

// ---------------- K3: flash attention (S^T, packed b64 P-writes) + fused corr branch ----------------
// grid (32, 7, B): y<6 -> flash split y; y==6 -> channel-attn logits block (n0 = x*128).
__global__ __launch_bounds__(256) void flash_kernel(
    const short* __restrict__ Qb, const short* __restrict__ Kb,
    const short* __restrict__ Vcn, short* __restrict__ opart, float* __restrict__ lsum,
    const short* __restrict__ q2b, const short* __restrict__ k2b, float* __restrict__ L2M)
{
  __shared__ short lds_s[24576];   // kt dbuf 2*4096 | vs dbuf 2*4096 | ps 128*64
  const int b    = blockIdx.z;
  const int s    = blockIdx.y;
  const int tid  = threadIdx.x;
  const int w    = tid >> 6;
  const int lane = tid & 63;
  const int L15  = lane & 15;
  const int quad = lane >> 4;

  if (s == 6) {                    // ---- corr: L[c][d] += sum_n q2[c,n] k2[d,n] ----
    const int n0 = blockIdx.x * 128;
    const short* qg = q2b + (size_t)b*262144;
    const short* kg = k2b + (size_t)b*262144;
    fx4 D[4] = {{0.f,0.f,0.f,0.f},{0.f,0.f,0.f,0.f},{0.f,0.f,0.f,0.f},{0.f,0.f,0.f,0.f}};
    #pragma unroll
    for (int kc = 0; kc < 4; ++kc) {
      bf16x8 a = *(const bf16x8*)&qg[(w*16 + L15)*4096 + n0 + kc*32 + quad*8];
      #pragma unroll
      for (int nt = 0; nt < 4; ++nt) {
        bf16x8 bb = *(const bf16x8*)&kg[(nt*16 + L15)*4096 + n0 + kc*32 + quad*8];
        D[nt] = __builtin_amdgcn_mfma_f32_16x16x32_bf16(a, bb, D[nt], 0, 0, 0);
      }
    }
    float* Lb = L2M + (size_t)b*4096;
    #pragma unroll
    for (int nt = 0; nt < 4; ++nt)
      #pragma unroll
      for (int r = 0; r < 4; ++r)
        atomicAdd(&Lb[(w*16 + quad*4 + r)*64 + nt*16 + L15], D[nt][r]);
    return;
  }

  short* ktb = lds_s;
  short* vsb = lds_s + 8192;
  short* ps  = lds_s + 16384;

  const int q0   = blockIdx.x << 7;
  const int t0   = (s < 4) ? s*11 : 44 + (s - 4)*10;
  const int cnt  = (s < 4) ? 11 : 10;
  const int jbase = w*32;

  const short* Qg = Qb  + (size_t)b*262144;
  const short* Kg = Kb  + (size_t)b*262144;
  const short* Vg = Vcn + (size_t)b*262144;

  bf16x8 qa[2][2];
  #pragma unroll
  for (int jt = 0; jt < 2; ++jt)
    #pragma unroll
    for (int h = 0; h < 2; ++h)
      qa[jt][h] = *(const bf16x8*)(Qg + (size_t)(q0 + jbase + jt*16 + L15)*64 + h*32 + quad*8);

  bf16x8 ones;
  #pragma unroll
  for (int u = 0; u < 8; ++u) ones[u] = (short)0x3F80;

  const int si  = tid >> 2;
  const int scb = (tid & 3) * 2;
  const int s0k = scb ^ (si & 7);
  const int s1k = s0k ^ 1;

  {
    const int i0 = t0 << 6;
    bf16x8 kr0 = *(const bf16x8*)(Kg + (size_t)(i0 + si)*64 + scb*8);
    bf16x8 kr1 = *(const bf16x8*)(Kg + (size_t)(i0 + si)*64 + scb*8 + 8);
    bf16x8 vr0 = *(const bf16x8*)(Vg + (size_t)si*4096 + i0 + (tid&3)*16);
    bf16x8 vr1 = *(const bf16x8*)(Vg + (size_t)si*4096 + i0 + (tid&3)*16 + 8);
    *(bf16x8*)(ktb + si*64 + s0k*8) = kr0;
    *(bf16x8*)(ktb + si*64 + s1k*8) = kr1;
    *(bf16x8*)(vsb + si*64 + s0k*8) = vr0;
    *(bf16x8*)(vsb + si*64 + s1k*8) = vr1;
  }
  __syncthreads();

  fx4 oacc[2][4];
  #pragma unroll
  for (int jt = 0; jt < 2; ++jt)
    #pragma unroll
    for (int ct = 0; ct < 4; ++ct) oacc[jt][ct] = (fx4){0.f,0.f,0.f,0.f};
  fx4 lacc[2] = {{0.f,0.f,0.f,0.f},{0.f,0.f,0.f,0.f}};

  const int cbx0 = quad       ^ (L15 & 7);
  const int cbx1 = (quad + 4) ^ (L15 & 7);
  const int jk   = L15 & 7;
  const int pu   = (quad >> 1);
  const int ph   = (quad & 1) << 2;

  for (int t = 0; t < cnt; ++t) {
    const short* kt = ktb + (t & 1)*4096;
    const short* vv = vsb + (t & 1)*4096;
    short* ktn = ktb + ((t + 1) & 1)*4096;
    short* vsn = vsb + ((t + 1) & 1)*4096;

    bf16x8 kr0, kr1, vr0, vr1;
    const bool pf = (t < cnt - 1);
    if (pf) {
      const int i0n = (t0 + t + 1) << 6;
      kr0 = *(const bf16x8*)(Kg + (size_t)(i0n + si)*64 + scb*8);
      kr1 = *(const bf16x8*)(Kg + (size_t)(i0n + si)*64 + scb*8 + 8);
      vr0 = *(const bf16x8*)(Vg + (size_t)si*4096 + i0n + (tid&3)*16);
      vr1 = *(const bf16x8*)(Vg + (size_t)si*4096 + i0n + (tid&3)*16 + 8);
    }

    // S^T = K Q^T
    fx4 d2[4][2];
    #pragma unroll
    for (int mt = 0; mt < 4; ++mt)
      #pragma unroll
      for (int jt = 0; jt < 2; ++jt) d2[mt][jt] = (fx4){0.f,0.f,0.f,0.f};
    #pragma unroll
    for (int mt = 0; mt < 4; ++mt) {
      bf16x8 ak0 = *(const bf16x8*)(kt + (mt*16 + L15)*64 + cbx0*8);
      bf16x8 ak1 = *(const bf16x8*)(kt + (mt*16 + L15)*64 + cbx1*8);
      d2[mt][0] = __builtin_amdgcn_mfma_f32_16x16x32_bf16(ak0, qa[0][0], d2[mt][0], 0, 0, 0);
      d2[mt][1] = __builtin_amdgcn_mfma_f32_16x16x32_bf16(ak0, qa[1][0], d2[mt][1], 0, 0, 0);
      d2[mt][0] = __builtin_amdgcn_mfma_f32_16x16x32_bf16(ak1, qa[0][1], d2[mt][0], 0, 0, 0);
      d2[mt][1] = __builtin_amdgcn_mfma_f32_16x16x32_bf16(ak1, qa[1][1], d2[mt][1], 0, 0, 0);
    }

    // raw exp; packed b64 P-writes
    #pragma unroll
    for (int mt = 0; mt < 4; ++mt) {
      const int slot0 = ((mt*2 + pu) ^ jk) << 3;
      #pragma unroll
      for (int jt = 0; jt < 2; ++jt) {
        const int j = jbase + jt*16 + L15;
        sh4 pv;
        pv.x = f2bf_fast(__expf(d2[mt][jt][0]));
        pv.y = f2bf_fast(__expf(d2[mt][jt][1]));
        pv.z = f2bf_fast(__expf(d2[mt][jt][2]));
        pv.w = f2bf_fast(__expf(d2[mt][jt][3]));
        *(sh4*)&ps[j*64 + slot0 + ph] = pv;
      }
    }

    bf16x8 pb[2][2];
    #pragma unroll
    for (int jt = 0; jt < 2; ++jt) {
      const int jrow = jbase + jt*16 + L15;
      pb[jt][0] = *(const bf16x8*)&ps[jrow*64 + (((quad    ) ^ jk) << 3)];
      pb[jt][1] = *(const bf16x8*)&ps[jrow*64 + (((quad + 4) ^ jk) << 3)];
    }

    #pragma unroll
    for (int jt = 0; jt < 2; ++jt) {
      lacc[jt] = __builtin_amdgcn_mfma_f32_16x16x32_bf16(ones, pb[jt][0], lacc[jt], 0, 0, 0);
      lacc[jt] = __builtin_amdgcn_mfma_f32_16x16x32_bf16(ones, pb[jt][1], lacc[jt], 0, 0, 0);
    }

    #pragma unroll
    for (int ct = 0; ct < 4; ++ct) {
      bf16x8 va0 = *(const bf16x8*)(vv + (ct*16 + L15)*64 + cbx0*8);
      bf16x8 va1 = *(const bf16x8*)(vv + (ct*16 + L15)*64 + cbx1*8);
      #pragma unroll
      for (int jt = 0; jt < 2; ++jt) {
        oacc[jt][ct] = __builtin_amdgcn_mfma_f32_16x16x32_bf16(va0, pb[jt][0], oacc[jt][ct], 0, 0, 0);
        oacc[jt][ct] = __builtin_amdgcn_mfma_f32_16x16x32_bf16(va1, pb[jt][1], oacc[jt][ct], 0, 0, 0);
      }
    }

    if (pf) {
      *(bf16x8*)(ktn + si*64 + s0k*8) = kr0;
      *(bf16x8*)(ktn + si*64 + s1k*8) = kr1;
      *(bf16x8*)(vsn + si*64 + s0k*8) = vr0;
      *(bf16x8*)(vsn + si*64 + s1k*8) = vr1;
    }
    __syncthreads();
  }

  const size_t srow = ((size_t)(b*6 + s)*4096) + q0;
  #pragma unroll
  for (int jt = 0; jt < 2; ++jt) {
    const size_t nrow = srow + jbase + jt*16 + L15;
    #pragma unroll
    for (int ct = 0; ct < 4; ++ct) {
      sh4 sv;
      sv.x = f2bf(oacc[jt][ct][0]); sv.y = f2bf(oacc[jt][ct][1]);
      sv.z = f2bf(oacc[jt][ct][2]); sv.w = f2bf(oacc[jt][ct][3]);
      *(sh4*)&opart[nrow*64 + ct*16 + quad*4] = sv;
    }
    if (quad == 0) lsum[nrow] = lacc[jt][0];
  }
}

// ---------------- K5: fused channel-softmax + merge + out2 + final conv ----------------
// grid (128 n-tiles of 32, B), block 256. p2 (8KB) + cat 32x128 (8KB) in LDS, xor-swizzled.
__global__ __launch_bounds__(256) void tail_kernel(
    const short* __restrict__ opart, const float* __restrict__ lsum,
    const float* __restrict__ l2m, const short* __restrict__ vnc,
    const short* __restrict__ w1b, const float* __restrict__ b1,
    float* __restrict__ sml)
{
  __shared__ short p2[4096];
  __shared__ short cat[4096];
  const int b    = blockIdx.y;
  const int n0   = blockIdx.x << 5;
  const int tid  = threadIdx.x;
  const int w    = tid >> 6;
  const int lane = tid & 63;
  const int L15  = lane & 15;
  const int quad = lane >> 4;

  // phase 0: channel softmax (redundant per block, tiny): row c = tid (<64)
  if (tid < 64) {
    const float* Lr = l2m + (size_t)b*4096 + tid*64;
    float vrow[64];
    float mx = -1e30f;
    #pragma unroll
    for (int d4 = 0; d4 < 16; ++d4) {
      float4 v4 = *(const float4*)&Lr[d4*4];
      vrow[d4*4+0] = v4.x; vrow[d4*4+1] = v4.y; vrow[d4*4+2] = v4.z; vrow[d4*4+3] = v4.w;
      mx = fmaxf(mx, fmaxf(fmaxf(v4.x, v4.y), fmaxf(v4.z, v4.w)));
    }
    float sme = 0.f;
    #pragma unroll
    for (int d = 0; d < 64; ++d) { vrow[d] = __expf(vrow[d] - mx); sme += vrow[d]; }
    const float inv = 1.0f / sme;
    const int key = tid & 7;
    #pragma unroll
    for (int g = 0; g < 8; ++g) {
      bf16x8 pk;
      #pragma unroll
      for (int u = 0; u < 8; ++u) pk[u] = f2bf(vrow[g*8 + u] * inv);
      *(bf16x8*)&p2[tid*64 + ((g ^ key) << 3)] = pk;
    }
  }

  // phase 1: merge 6 flash partials -> cat cols 0..63 (32 rows x 8 threads)
  {
    const int nl = tid >> 3;
    const int c0 = (tid & 7) << 3;
    const int n  = n0 + nl;
    float l = 0.f;
    #pragma unroll
    for (int sp = 0; sp < 6; ++sp) l += lsum[((size_t)(b*6 + sp)*4096) + n];
    const float inv = 1.0f / l;
    float acc[8];
    #pragma unroll
    for (int u = 0; u < 8; ++u) acc[u] = 0.f;
    #pragma unroll
    for (int sp = 0; sp < 6; ++sp) {
      bf16x8 A0 = *(const bf16x8*)&opart[(((size_t)(b*6 + sp)*4096) + n)*64 + c0];
      #pragma unroll
      for (int u = 0; u < 8; ++u) acc[u] += bf2f(A0[u]);
    }
    const int key = nl & 7;
    const int g = (c0 >> 3) ^ key;
    bf16x8 s0;
    #pragma unroll
    for (int u = 0; u < 8; ++u) s0[u] = f2bf(acc[u]*inv);
    *(bf16x8*)&cat[nl*128 + (g << 3)] = s0;
  }
  __syncthreads();   // p2 ready; cat cols 0..63 done

  // phase 2: out2 = P2 @ V -> cat cols 64..127 (wave w: nsub = w&1, m-half = w>>1)
  {
    const int nl  = (w & 1)*16 + L15;
    const int n   = n0 + nl;
    const int mh  = w >> 1;
    const int key = L15 & 7;
    bf16x8 vb0 = *(const bf16x8*)&vnc[((size_t)b*4096 + n)*64 + quad*8];
    bf16x8 vb1 = *(const bf16x8*)&vnc[((size_t)b*4096 + n)*64 + quad*8 + 32];
    #pragma unroll
    for (int mi = 0; mi < 2; ++mi) {
      const int mt = mh*2 + mi;
      bf16x8 a0 = *(const bf16x8*)&p2[(mt*16 + L15)*64 + (((quad    ) ^ key) << 3)];
      bf16x8 a1 = *(const bf16x8*)&p2[(mt*16 + L15)*64 + (((quad + 4) ^ key) << 3)];
      fx4 d = {0.f,0.f,0.f,0.f};
      d = __builtin_amdgcn_mfma_f32_16x16x32_bf16(a0, vb0, d, 0, 0, 0);
      d = __builtin_amdgcn_mfma_f32_16x16x32_bf16(a1, vb1, d, 0, 0, 0);
      const int c = 64 + mt*16 + quad*4;
      const int g = (c >> 3) ^ key;
      sh4 sv; sv.x = f2bf(d[0]); sv.y = f2bf(d[1]); sv.z = f2bf(d[2]); sv.w = f2bf(d[3]);
      *(sh4*)&cat[nl*128 + (g << 3) + (quad & 1)*4] = sv;
    }
  }
  __syncthreads();

  // phase 3: conv 128->64 (wave w: nsub = w&1, m-half = w>>1), fp32 [c][n] out
  {
    const int nl  = (w & 1)*16 + L15;
    const int mh  = w >> 1;
    const int key = L15 & 7;
    bf16x8 bfr[4];
    #pragma unroll
    for (int kc = 0; kc < 4; ++kc) {
      const int g = (kc*4 + quad) ^ key;
      bfr[kc] = *(const bf16x8*)&cat[nl*128 + (g << 3)];
    }
    #pragma unroll
    for (int mi = 0; mi < 2; ++mi) {
      const int mt = mh*2 + mi;
      fx4 d = {0.f,0.f,0.f,0.f};
      #pragma unroll
      for (int kc = 0; kc < 4; ++kc) {
        bf16x8 a = *(const bf16x8*)&w1b[(mt*16 + L15)*128 + kc*32 + quad*8];
        d = __builtin_amdgcn_mfma_f32_16x16x32_bf16(a, bfr[kc], d, 0, 0, 0);
      }
      const int ob = mt*16 + quad*4;
      #pragma unroll
      for (int r = 0; r < 4; ++r)
        sml[((size_t)b*64 + ob + r)*4096 + n0 + nl] = d[r] + b1[ob + r];
    }
  }
}

// ---------------- K6: bilinear 2x upsample + residual — 2 horizontal pixels/thread ----------------
__global__ __launch_bounds__(256) void upsample_kernel(
    const float* __restrict__ sml, const float* __restrict__ x, float* __restrict__ out)
{
  int idx = blockIdx.x*256 + threadIdx.x;     // 2,097,152 threads
  int jp = idx & 63;
  int I  = (idx >> 6) & 127;
  int bo = idx >> 13;
  int ih = I >> 1;
  int i0, i1; float wi0, wi1;
  if (I & 1) { i0 = ih;                 i1 = (ih < 63) ? ih+1 : 63; wi0 = 0.75f; wi1 = 0.25f; }
  else       { i0 = (ih > 0) ? ih-1 : 0; i1 = ih;                   wi0 = 0.25f; wi1 = 0.75f; }
  const int jm = (jp > 0)  ? jp-1 : 0;
  const int jx = (jp < 63) ? jp+1 : 63;
  const float* sp = sml + (size_t)bo*4096;
  float a0 = sp[i0*64 + jm], a1 = sp[i0*64 + jp], a2 = sp[i0*64 + jx];
  float b0 = sp[i1*64 + jm], b1v = sp[i1*64 + jp], b2v = sp[i1*64 + jx];
  float re0 = wi0*(0.25f*a0 + 0.75f*a1) + wi1*(0.25f*b0 + 0.75f*b1v);
  float re1 = wi0*(0.75f*a1 + 0.25f*a2) + wi1*(0.75f*b1v + 0.25f*b2v);
  const size_t obase = ((size_t)bo*128 + I)*128 + jp*2;
  float2 xr = *(const float2*)&x[obase];
  *(float2*)&out[obase] = make_float2(re0 + xr.x, re1 + xr.y);
}

// ---------------- host ----------------
extern "C" void kernel_launch(void* const* d_in, const int* in_sizes, int n_in,
                              void* d_out, int out_size, void* d_ws, size_t ws_size,
                              hipStream_t stream) {
  const float* x     = (const float*)d_in[0];
  const float* gamma = (const float*)d_in[1];
  const float* beta  = (const float*)d_in[2];
  const float* pm_w  = (const float*)d_in[3];
  const float* pm_b  = (const float*)d_in[4];
  const float* w2 = (const float*)d_in[5];  const float* b2 = (const float*)d_in[6];
  const float* w3 = (const float*)d_in[7];  const float* b3 = (const float*)d_in[8];
  const float* w4 = (const float*)d_in[9];  const float* b4 = (const float*)d_in[10];
  const float* w5 = (const float*)d_in[11]; const float* b5 = (const float*)d_in[12];
  const float* w6 = (const float*)d_in[13]; const float* b6 = (const float*)d_in[14];
  const float* w1 = (const float*)d_in[15]; const float* b1 = (const float*)d_in[16];
  char* wsb  = (char*)d_ws;
  float* out = (float*)d_out;

  short* opart = (short*)(wsb + OPART_B);
  float* lsum  = (float*)(wsb + LSUM_B);
  float* sml   = (float*)(wsb + SMALL_B);
  float* l2m   = (float*)(wsb + L2M_B);
  short* pmb   = (short*)(wsb + PMB_B);
  short* w2b   = (short*)(wsb + W2B_B);
  short* w3b   = (short*)(wsb + W3B_B);
  short* w4b   = (short*)(wsb + W4B_B);
  short* w5b   = (short*)(wsb + W5B_B);
  short* w6b   = (short*)(wsb + W6B_B);
  short* w1b   = (short*)(wsb + W1B_B);
  short* qb    = (short*)(wsb + QB_B);
  short* kb    = (short*)(wsb + KB_B);
  short* vcn   = (short*)(wsb + VCN_B);
  short* vnc   = (short*)(wsb + VNC_B);
  short* q2b   = (short*)(wsb + Q2B_B);
  short* k2b   = (short*)(wsb + K2B_B);

  prep_kernel<<<dim3(64), dim3(256), 0, stream>>>(pm_w, w2, w3, w4, w5, w6, w1, wsb);
  patchproj_kernel<<<dim3(128,4), dim3(256), 0, stream>>>(x, gamma, beta, pmb, pm_b,
      w2b, w3b, w4b, w5b, w6b, b2, b3, b4, b5, b6, qb, kb, vcn, vnc, q2b, k2b);
  flash_kernel<<<dim3(32,7,4), dim3(256), 0, stream>>>(qb, kb, vcn, opart, lsum, q2b, k2b, l2m);
  tail_kernel<<<dim3(128,4), dim3(256), 0, stream>>>(opart, lsum, l2m, vnc, w1b, b1, sml);
  upsample_kernel<<<dim3(8192), dim3(256), 0, stream>>>(sml, x, out);
}